// Round 8
// baseline (199.130 us; speedup 1.0000x reference)
//
#include <hip/hip_runtime.h>

#define HW 96
#define NPIX 9216
#define QN 192
#define ASTRIDE 52
#define SCALE 0.17677669529663687f
#define NT 576
#define HALO_N 132          // 12 rows x 11 cols

// XOR-swizzled LDS word address: linear rows of 64 words, 16B slot XOR'd by
// row&7 so strided row access spreads across banks.
__device__ __forceinline__ int swz(int row, int col) {
    return row * 64 + (col ^ ((row & 7) << 2));
}

// halo slot hp (0..131) -> clamped global pixel index
__device__ __forceinline__ int halo_pix(int hp, int hr0, int hc0) {
    int hi = (hp * 745) >> 13;            // hp / 11 for hp < 8192
    int hj = hp - hi * 11;
    int gi = hr0 + hi; gi = gi < 0 ? 0 : (gi > 95 ? 95 : gi);
    int gj = hc0 + hj; gj = gj < 0 ? 0 : (gj > 95 ? 95 : gj);
    return gi * HW + gj;
}

// 18px x 192j x 64c GEMM. xs rows 0..17; weights in wbig with row mapping
// j -> j (j<132) | j+64 (j>=132). 576 thr: pxg=t%9 (2 px), jo=t/9 (3 j).
__device__ __forceinline__ void qkv_gemm(const float* __restrict__ xs,
                                         const float* __restrict__ wbig,
                                         const float* __restrict__ qb,
                                         float* __restrict__ qkv,
                                         int i0, int j0c, int t)
{
    const int pxg = t % 9, jo = t / 9;
    const int jb = jo * 3;
    int wr[3];
    #pragma unroll
    for (int jj = 0; jj < 3; ++jj) {
        int j = jb + jj;
        wr[jj] = j + (j >= 132 ? 64 : 0);
    }
    float acc[2][3];
    #pragma unroll
    for (int jj = 0; jj < 3; ++jj) {
        float bv = qb[jb + jj];
        acc[0][jj] = bv; acc[1][jj] = bv;
    }
    #pragma unroll
    for (int cc = 0; cc < 16; ++cc) {
        float4 xv[2], wv[3];
        #pragma unroll
        for (int ii = 0; ii < 2; ++ii)
            xv[ii] = *(const float4*)&xs[swz(pxg * 2 + ii, cc * 4)];
        #pragma unroll
        for (int jj = 0; jj < 3; ++jj)
            wv[jj] = *(const float4*)&wbig[swz(wr[jj], cc * 4)];
        #pragma unroll
        for (int ii = 0; ii < 2; ++ii)
            #pragma unroll
            for (int jj = 0; jj < 3; ++jj) {
                acc[ii][jj] = fmaf(xv[ii].x, wv[jj].x, acc[ii][jj]);
                acc[ii][jj] = fmaf(xv[ii].y, wv[jj].y, acc[ii][jj]);
                acc[ii][jj] = fmaf(xv[ii].z, wv[jj].z, acc[ii][jj]);
                acc[ii][jj] = fmaf(xv[ii].w, wv[jj].w, acc[ii][jj]);
            }
    }
    #pragma unroll
    for (int ii = 0; ii < 2; ++ii) {
        int px = pxg * 2 + ii;
        float* o = qkv + ((i0 + px / 3) * HW + j0c + px % 3) * QN + jb;
        o[0] = acc[ii][0]; o[1] = acc[ii][1]; o[2] = acc[ii][2];
    }
}

// Stage-0 qkv: simple (weights linear rows 0..191 in its own ws).
__global__ __launch_bounds__(NT, 5) void k_qkv0(const float* __restrict__ x,
                                                const float* __restrict__ qw,
                                                const float* __restrict__ qb,
                                                float* __restrict__ qkv)
{
    __shared__ float xs[18 * 64];
    __shared__ float ws[QN * 64];
    const int t = threadIdx.x;
    const int tile = ((blockIdx.x & 7) << 6) | (blockIdx.x >> 3);
    const int i0 = (tile >> 5) * 6, j0c = (tile & 31) * 3;
    #pragma unroll
    for (int it = 0; it < 2; ++it) {
        int l = it * NT + t;
        int px = l % 18, c = l / 18;
        xs[swz(px, c)] = x[c * NPIX + (i0 + px / 3) * HW + j0c + px % 3];
    }
    #pragma unroll
    for (int it = 0; it < 6; ++it) {
        int l = it * NT + t;
        if (l < 3072) {
            int j = l >> 4, cs = (l & 15) << 2;
            *(float4*)&ws[swz(j, cs)] = *(const float4*)&qw[j * 64 + cs];
        }
    }
    __syncthreads();
    // inline gemm against linear ws rows (no split mapping)
    const int pxg = t % 9, jo = t / 9;
    const int jb = jo * 3;
    float acc[2][3];
    #pragma unroll
    for (int jj = 0; jj < 3; ++jj) {
        float bv = qb[jb + jj];
        acc[0][jj] = bv; acc[1][jj] = bv;
    }
    #pragma unroll
    for (int cc = 0; cc < 16; ++cc) {
        float4 xv[2], wv[3];
        #pragma unroll
        for (int ii = 0; ii < 2; ++ii)
            xv[ii] = *(const float4*)&xs[swz(pxg * 2 + ii, cc * 4)];
        #pragma unroll
        for (int jj = 0; jj < 3; ++jj)
            wv[jj] = *(const float4*)&ws[swz(jb + jj, cc * 4)];
        #pragma unroll
        for (int ii = 0; ii < 2; ++ii)
            #pragma unroll
            for (int jj = 0; jj < 3; ++jj) {
                acc[ii][jj] = fmaf(xv[ii].x, wv[jj].x, acc[ii][jj]);
                acc[ii][jj] = fmaf(xv[ii].y, wv[jj].y, acc[ii][jj]);
                acc[ii][jj] = fmaf(xv[ii].z, wv[jj].z, acc[ii][jj]);
                acc[ii][jj] = fmaf(xv[ii].w, wv[jj].w, acc[ii][jj]);
            }
    }
    #pragma unroll
    for (int ii = 0; ii < 2; ++ii) {
        int px = pxg * 2 + ii;
        float* o = qkv + ((i0 + px / 3) * HW + j0c + px % 3) * QN + jb;
        o[0] = acc[ii][0]; o[1] = acc[ii][1]; o[2] = acc[ii][2];
    }
}

// Fused stage, single-burst load version.
// big rows: 0..131 = K-halo -> V-halo -> qw rows 0..131 (phased)
//           132..195 = pw (written phase 1, read in proj)
//           196..255 = qw rows 132..191 (written phase 1, read in qkv_gemm)
template <int HASPREV, int LAST>
__global__ __launch_bounds__(NT, 5) void k_stage(const float* __restrict__ qkv,
                                                 const float* __restrict__ rpb,
                                                 const float* __restrict__ prev,
                                                 float* __restrict__ cur,
                                                 const float* __restrict__ pw,
                                                 const float* __restrict__ pb,
                                                 const float* __restrict__ qw,
                                                 const float* __restrict__ qb,
                                                 float* __restrict__ qkvn,
                                                 float* __restrict__ outp)
{
    __shared__ float smem[16384 + 36 * ASTRIDE + 18 * 64];
    float* big   = smem;                          // 256 rows x 64
    float* att_s = smem + 16384;                  // 36 x 52
    float* qsx   = smem + 16384 + 36 * ASTRIDE;   // qs (QK) then xs (proj) 18x64

    const int t = threadIdx.x;
    const int tile = ((blockIdx.x & 7) << 6) | (blockIdx.x >> 3);
    const int i0 = (tile >> 5) * 6, j0c = (tile & 31) * 3;
    const int hr0 = i0 - 3, hc0 = j0c - 4;

    const int ln = t & 15, g = t >> 4;
    const int h = g & 1, pl = g >> 1;
    const int i = i0 + pl / 3, jx = j0c + pl % 3;
    const int p = i * HW + jx;
    int si = i - 3;  si = si < 0 ? 0 : (si > 89 ? 89 : si);
    int sj = jx - 3; sj = sj < 0 ? 0 : (sj > 89 ? 89 : sj);

    // ================= phase 1: single burst of ALL global loads ==========
    const int c4 = (t & 15) << 2;
    int hpix[4], hps[4];
    #pragma unroll
    for (int it = 0; it < 4; ++it) {
        hps[it] = it * 36 + (t >> 4);
        hpix[it] = halo_pix(hps[it] < HALO_N ? hps[it] : 0, hr0, hc0);
    }
    // (a) K-halo (needed first -> issued first)
    float4 kreg[4];
    #pragma unroll
    for (int it = 0; it < 4; ++it)
        if (hps[it] < HALO_N)
            kreg[it] = *(const float4*)&qkv[hpix[it] * QN + 64 + c4];
    // (b) Q tile
    float4 qreg;
    if (t < 288) {
        int gq = t >> 3, dc = (t & 7) << 2;
        int plq = gq >> 1;
        int pq = (i0 + plq / 3) * HW + j0c + plq % 3;
        qreg = *(const float4*)&qkv[pq * QN + (gq & 1) * 32 + dc];
    }
    // (c) pw -> rows 132..195
    float4 pwreg[2];
    #pragma unroll
    for (int it = 0; it < 2; ++it) {
        int l = it * NT + t;
        if (l < 1024)
            pwreg[it] = *(const float4*)&pw[(l >> 4) * 64 + ((l & 15) << 2)];
    }
    // (d) qw rows 132..191 -> rows 196..255
    float4 qwh[2];
    if (!LAST) {
        #pragma unroll
        for (int it = 0; it < 2; ++it) {
            int l = it * NT + t;
            if (l < 960)
                qwh[it] = *(const float4*)&qw[(132 + (l >> 4)) * 64 + ((l & 15) << 2)];
        }
    }
    // (e) V-halo into regs (LDS-written after B2)
    float4 vreg[4];
    #pragma unroll
    for (int it = 0; it < 4; ++it)
        if (hps[it] < HALO_N)
            vreg[it] = *(const float4*)&qkv[hpix[it] * QN + 128 + c4];
    // (f) prev attention
    float pr[4] = {0.f, 0.f, 0.f, 0.f};
    if (HASPREV) {
        #pragma unroll
        for (int k = 0; k < 4; ++k)
            pr[k] = prev[(p * 2 + h) * ASTRIDE + ((k << 4) | ln)];
    }
    // (g) qw rows 0..131 into regs (LDS-written after B4)
    float4 qwl[4];
    if (!LAST) {
        #pragma unroll
        for (int it = 0; it < 4; ++it) {
            int l = it * NT + t;
            if (l < 2112)
                qwl[it] = *(const float4*)&qw[(l >> 4) * 64 + ((l & 15) << 2)];
        }
    }
    // ---- LDS writes of phase-1-resident data (K, Q, pw, qw_hi) ----
    #pragma unroll
    for (int it = 0; it < 4; ++it)
        if (hps[it] < HALO_N)
            *(float4*)&big[swz(hps[it], c4)] = kreg[it];
    if (t < 288) {
        int gq = t >> 3, dc = (t & 7) << 2;
        *(float4*)&qsx[gq * 32 + dc] = qreg;
    }
    #pragma unroll
    for (int it = 0; it < 2; ++it) {
        int l = it * NT + t;
        if (l < 1024)
            *(float4*)&big[swz(132 + (l >> 4), (l & 15) << 2)] = pwreg[it];
    }
    if (!LAST) {
        #pragma unroll
        for (int it = 0; it < 2; ++it) {
            int l = it * NT + t;
            if (l < 960)
                *(float4*)&big[swz(196 + (l >> 4), (l & 15) << 2)] = qwh[it];
        }
    }
    __syncthreads();                                            // B1
    // ================= QK (LDS) ===========================================
    const int hbase = (si - hr0) * 11 + (sj - hc0);
    int hofs[4], rbidx[4], okm[4];
    #pragma unroll
    for (int k = 0; k < 4; ++k) {
        int n = (k << 4) | ln;
        okm[k] = (n <= 48);
        int nn = okm[k] ? n : 0;
        int a = (nn * 147) >> 10;                 // nn / 7
        int b = nn - a * 7;
        hofs[k] = hbase + a * 11 + b;
        rbidx[k] = a * 13 + b;
    }
    float s0 = 0.f, s1 = 0.f, s2 = 0.f, s3 = 0.f;
    #pragma unroll
    for (int dc = 0; dc < 8; ++dc) {
        float4 qv = *(const float4*)&qsx[g * 32 + dc * 4];
        float4 k0 = *(const float4*)&big[swz(hofs[0], dc * 4)];
        float4 k1 = *(const float4*)&big[swz(hofs[1], dc * 4)];
        float4 k2 = *(const float4*)&big[swz(hofs[2], dc * 4)];
        float4 k3 = *(const float4*)&big[swz(hofs[3], dc * 4)];
        s0 = fmaf(qv.x, k0.x, s0); s0 = fmaf(qv.y, k0.y, s0);
        s0 = fmaf(qv.z, k0.z, s0); s0 = fmaf(qv.w, k0.w, s0);
        s1 = fmaf(qv.x, k1.x, s1); s1 = fmaf(qv.y, k1.y, s1);
        s1 = fmaf(qv.z, k1.z, s1); s1 = fmaf(qv.w, k1.w, s1);
        s2 = fmaf(qv.x, k2.x, s2); s2 = fmaf(qv.y, k2.y, s2);
        s2 = fmaf(qv.z, k2.z, s2); s2 = fmaf(qv.w, k2.w, s2);
        s3 = fmaf(qv.x, k3.x, s3); s3 = fmaf(qv.y, k3.y, s3);
        s3 = fmaf(qv.z, k3.z, s3); s3 = fmaf(qv.w, k3.w, s3);
    }
    float lg[4] = {s0, s1, s2, s3};
    {
        const float* rp = rpb + h * 169;
        const int rbase = (si - i + 6) * 13 + (sj - jx + 6);
        #pragma unroll
        for (int k = 0; k < 4; ++k) {
            float bv = rp[rbase + rbidx[k]];
            float l2 = fmaf(lg[k], SCALE, bv + pr[k]);
            lg[k] = okm[k] ? l2 : -1e30f;
        }
    }
    float mx = fmaxf(fmaxf(lg[0], lg[1]), fmaxf(lg[2], lg[3]));
    mx = fmaxf(mx, __shfl_xor(mx, 1));
    mx = fmaxf(mx, __shfl_xor(mx, 2));
    mx = fmaxf(mx, __shfl_xor(mx, 4));
    mx = fmaxf(mx, __shfl_xor(mx, 8));
    float wk[4];
    float sum = 0.f;
    #pragma unroll
    for (int k = 0; k < 4; ++k) { wk[k] = expf(lg[k] - mx); sum += wk[k]; }
    sum += __shfl_xor(sum, 1);
    sum += __shfl_xor(sum, 2);
    sum += __shfl_xor(sum, 4);
    sum += __shfl_xor(sum, 8);
    const float inv = 1.f / sum;
    wk[0] *= inv; wk[1] *= inv; wk[2] *= inv; wk[3] *= inv;
    // publish weights (same-wave LDS ordering; no barrier needed before reads)
    att_s[g * ASTRIDE + ln]      = wk[0];
    att_s[g * ASTRIDE + 16 + ln] = wk[1];
    att_s[g * ASTRIDE + 32 + ln] = wk[2];
    if (ln == 0) att_s[g * ASTRIDE + 48] = wk[3];
    if (!LAST) {
        const int gp = p * 2 + h;
        if (ln < 12)
            *(float4*)&cur[gp * ASTRIDE + ln * 4] =
                *(const float4*)&att_s[g * ASTRIDE + ln * 4];
        else if (ln == 12)
            cur[gp * ASTRIDE + 48] = att_s[g * ASTRIDE + 48];
    }
    __syncthreads();                                            // B2 (K reads done)
    // V-halo regs -> LDS
    #pragma unroll
    for (int it = 0; it < 4; ++it)
        if (hps[it] < HALO_N)
            *(float4*)&big[swz(hps[it], c4)] = vreg[it];
    __syncthreads();                                            // B3
    // ================= PV (LDS): lane owns dims {ln*2, ln*2+1} ============
    {
        const int vcol = h * 32 + ln * 2;
        float a0 = 0.f, a1 = 0.f;
        #pragma unroll
        for (int kk = 0; kk < 12; ++kk) {
            float4 w4 = *(const float4*)&att_s[g * ASTRIDE + kk * 4];
            #pragma unroll
            for (int c = 0; c < 4; ++c) {
                int n = kk * 4 + c;
                int a = n / 7, b = n % 7;        // compile-time after unroll
                float w = (c == 0) ? w4.x : (c == 1) ? w4.y : (c == 2) ? w4.z : w4.w;
                float2 v = *(const float2*)&big[swz(hbase + a * 11 + b, vcol)];
                a0 = fmaf(w, v.x, a0); a1 = fmaf(w, v.y, a1);
            }
        }
        float w48 = att_s[g * ASTRIDE + 48];
        float2 v48 = *(const float2*)&big[swz(hbase + 6 * 11 + 6, vcol)];
        a0 = fmaf(w48, v48.x, a0); a1 = fmaf(w48, v48.y, a1);
        *(float2*)&qsx[swz(pl, vcol)] = make_float2(a0, a1);
    }
    __syncthreads();                                            // B4 (V reads done, xs ready)
    // qw rows 0..131 regs -> LDS (overwrites V-halo region), overlapped w/ proj
    if (!LAST) {
        #pragma unroll
        for (int it = 0; it < 4; ++it) {
            int l = it * NT + t;
            if (l < 2112)
                *(float4*)&big[swz(l >> 4, (l & 15) << 2)] = qwl[it];
        }
    }
    // ================= proj: pxg=t%9 (2 px), jo=t/9 (1 j) =================
    const int pxg = t % 9, jo = t / 9;
    float pa0 = pb[jo], pa1 = pa0;
    #pragma unroll
    for (int cc = 0; cc < 16; ++cc) {
        float4 xv0 = *(const float4*)&qsx[swz(pxg * 2, cc * 4)];
        float4 xv1 = *(const float4*)&qsx[swz(pxg * 2 + 1, cc * 4)];
        float4 wv  = *(const float4*)&big[swz(132 + jo, cc * 4)];
        pa0 = fmaf(xv0.x, wv.x, pa0); pa0 = fmaf(xv0.y, wv.y, pa0);
        pa0 = fmaf(xv0.z, wv.z, pa0); pa0 = fmaf(xv0.w, wv.w, pa0);
        pa1 = fmaf(xv1.x, wv.x, pa1); pa1 = fmaf(xv1.y, wv.y, pa1);
        pa1 = fmaf(xv1.z, wv.z, pa1); pa1 = fmaf(xv1.w, wv.w, pa1);
    }
    __syncthreads();                                            // B5 (xs reads + qw_lo writes done)
    qsx[swz(pxg * 2, jo)]     = pa0;
    qsx[swz(pxg * 2 + 1, jo)] = pa1;
    __syncthreads();                                            // B6 (xh visible)
    if (LAST) {
        #pragma unroll
        for (int it = 0; it < 2; ++it) {
            int l = it * NT + t;
            int px = l % 18, c = l / 18;
            outp[c * NPIX + (i0 + px / 3) * HW + j0c + px % 3] = qsx[swz(px, c)];
        }
        return;
    }
    qkv_gemm(qsx, big, qb, qkvn, i0, j0c, t);
}

extern "C" void kernel_launch(void* const* d_in, const int* in_sizes, int n_in,
                              void* d_out, int out_size, void* d_ws, size_t ws_size,
                              hipStream_t stream)
{
    const float* x   = (const float*)d_in[0];
    const float* qw  = (const float*)d_in[1];   // (3,192,64)
    const float* qb  = (const float*)d_in[2];   // (3,192)
    const float* pw  = (const float*)d_in[3];   // (3,64,64)
    const float* pb  = (const float*)d_in[4];   // (3,64)
    const float* rpb = (const float*)d_in[5];   // (3,2,13,13)
    float* out = (float*)d_out;
    float* ws  = (float*)d_ws;

    float* qkvA = ws;                    // 1,769,472 floats
    float* qkvB = qkvA + 1769472;        // 1,769,472
    float* attA = qkvB + 1769472;        //   958,464 (18432 * 52)
    float* attB = attA + 958464;         //   958,464  (~21.8 MB total)

    k_qkv0<<<512, NT, 0, stream>>>(x, qw, qb, qkvA);
    k_stage<0, 0><<<512, NT, 0, stream>>>(qkvA, rpb,       nullptr, attA,
                                          pw,        pb,       qw + 12288, qb + 192, qkvB, nullptr);
    k_stage<1, 0><<<512, NT, 0, stream>>>(qkvB, rpb + 338, attA,    attB,
                                          pw + 4096, pb + 64,  qw + 24576, qb + 384, qkvA, nullptr);
    k_stage<1, 1><<<512, NT, 0, stream>>>(qkvA, rpb + 676, attB,    nullptr,
                                          pw + 8192, pb + 128, nullptr,    nullptr,  nullptr, out);
}

// Round 9
// 169.416 us; speedup vs baseline: 1.1754x; 1.1754x over previous
//
#include <hip/hip_runtime.h>

#define HW 96
#define NPIX 9216
#define QN 192
#define ASTRIDE 52
#define SCALE 0.17677669529663687f
#define NT 576
#define HALO_N 132          // 12 rows x 11 cols

// XOR-swizzled LDS word address: linear rows of 64 words, 16B slot XOR'd by
// row&7 so strided row access spreads across banks.
__device__ __forceinline__ int swz(int row, int col) {
    return row * 64 + (col ^ ((row & 7) << 2));
}

// halo slot hp (0..131) -> clamped global pixel index
__device__ __forceinline__ int halo_pix(int hp, int hr0, int hc0) {
    int hi = (hp * 745) >> 13;            // hp / 11 for hp < 8192
    int hj = hp - hi * 11;
    int gi = hr0 + hi; gi = gi < 0 ? 0 : (gi > 95 ? 95 : gi);
    int gj = hc0 + hj; gj = gj < 0 ? 0 : (gj > 95 ? 95 : gj);
    return gi * HW + gj;
}

// Fused weight prep: wfuse[s] = qw[s+1] @ pw[s]  (192x64),
// bfuse[s] = qb[s+1] + qw[s+1] @ pb[s].  s = 0,1.
__global__ __launch_bounds__(256) void k_prep(const float* __restrict__ qw,
                                              const float* __restrict__ qb,
                                              const float* __restrict__ pw,
                                              const float* __restrict__ pb,
                                              float* __restrict__ wfuse,
                                              float* __restrict__ bfuse)
{
    const int idx = blockIdx.x * 256 + threadIdx.x;   // 0..24575
    const int s = idx / 12288;
    const int r = idx - s * 12288;
    const int j = r >> 6, m = r & 63;
    const float* qwp = qw + (s + 1) * 12288 + j * 64;
    const float* pwp = pw + s * 4096;
    float acc = 0.f;
    #pragma unroll 8
    for (int c = 0; c < 64; ++c)
        acc = fmaf(qwp[c], pwp[c * 64 + m], acc);
    wfuse[idx] = acc;
    if (m == 0) {
        const float* pbp = pb + s * 64;
        float b = qb[(s + 1) * 192 + j];
        #pragma unroll 8
        for (int c = 0; c < 64; ++c)
            b = fmaf(qwp[c], pbp[c], b);
        bfuse[s * 192 + j] = b;
    }
}

// 18px x 192j x 64c GEMM from LDS. 288 active threads: pxg=t%6 (3 px),
// jo=t/6 (4 j). Aligned float4 stores.
__device__ __forceinline__ void fused_gemm(const float* __restrict__ xs,
                                           const float* __restrict__ wbig,
                                           const float* __restrict__ bias,
                                           float* __restrict__ outq,
                                           int i0, int j0c, int t)
{
    if (t >= 288) return;
    const int pxg = t % 6, jo = t / 6;
    const int jb = jo * 4;
    float acc[3][4];
    #pragma unroll
    for (int jj = 0; jj < 4; ++jj) {
        float bv = bias[jb + jj];
        acc[0][jj] = bv; acc[1][jj] = bv; acc[2][jj] = bv;
    }
    #pragma unroll
    for (int cc = 0; cc < 16; ++cc) {
        float4 xv[3], wv[4];
        #pragma unroll
        for (int ii = 0; ii < 3; ++ii)
            xv[ii] = *(const float4*)&xs[swz(pxg * 3 + ii, cc * 4)];
        #pragma unroll
        for (int jj = 0; jj < 4; ++jj)
            wv[jj] = *(const float4*)&wbig[swz(jb + jj, cc * 4)];
        #pragma unroll
        for (int ii = 0; ii < 3; ++ii)
            #pragma unroll
            for (int jj = 0; jj < 4; ++jj) {
                acc[ii][jj] = fmaf(xv[ii].x, wv[jj].x, acc[ii][jj]);
                acc[ii][jj] = fmaf(xv[ii].y, wv[jj].y, acc[ii][jj]);
                acc[ii][jj] = fmaf(xv[ii].z, wv[jj].z, acc[ii][jj]);
                acc[ii][jj] = fmaf(xv[ii].w, wv[jj].w, acc[ii][jj]);
            }
    }
    #pragma unroll
    for (int ii = 0; ii < 3; ++ii) {
        int px = pxg * 3 + ii;
        *(float4*)&outq[((i0 + px / 3) * HW + j0c + px % 3) * QN + jb] =
            make_float4(acc[ii][0], acc[ii][1], acc[ii][2], acc[ii][3]);
    }
}

__global__ __launch_bounds__(NT, 5) void k_qkv0(const float* __restrict__ x,
                                                const float* __restrict__ qw,
                                                const float* __restrict__ qb,
                                                float* __restrict__ qkv)
{
    __shared__ float xs[18 * 64];
    __shared__ float ws[QN * 64];
    const int t = threadIdx.x;
    const int tile = ((blockIdx.x & 7) << 6) | (blockIdx.x >> 3);
    const int i0 = (tile >> 5) * 6, j0c = (tile & 31) * 3;
    #pragma unroll
    for (int it = 0; it < 2; ++it) {
        int l = it * NT + t;
        int px = l % 18, c = l / 18;
        xs[swz(px, c)] = x[c * NPIX + (i0 + px / 3) * HW + j0c + px % 3];
    }
    #pragma unroll
    for (int it = 0; it < 6; ++it) {
        int l = it * NT + t;
        if (l < 3072) {
            int j = l >> 4, cs = (l & 15) << 2;
            *(float4*)&ws[swz(j, cs)] = *(const float4*)&qw[j * 64 + cs];
        }
    }
    __syncthreads();
    fused_gemm(xs, ws, qb, qkv, i0, j0c, t);
}

// Fused stage: attention + (fused proj.qkv GEMM | final proj+output).
// big rows: 0..131 = K-halo -> V-halo -> W'lo (phased)
//           132..191 = W'hi  (non-LAST)   |   132..195 = pw (LAST)
template <int HASPREV, int LAST>
__global__ __launch_bounds__(NT, 5) void k_stage(const float* __restrict__ qkv,
                                                 const float* __restrict__ rpb,
                                                 const float* __restrict__ prev,
                                                 float* __restrict__ cur,
                                                 const float* __restrict__ wp,
                                                 const float* __restrict__ bp,
                                                 float* __restrict__ qkvn,
                                                 float* __restrict__ outp)
{
    __shared__ float smem[196 * 64 + 36 * ASTRIDE + 18 * 64];
    float* big   = smem;                          // 196 rows x 64
    float* att_s = smem + 196 * 64;               // 36 x 52
    float* qsx   = att_s + 36 * ASTRIDE;          // Q tile, then attn_out 18x64

    const int t = threadIdx.x;
    const int tile = ((blockIdx.x & 7) << 6) | (blockIdx.x >> 3);
    const int i0 = (tile >> 5) * 6, j0c = (tile & 31) * 3;
    const int hr0 = i0 - 3, hc0 = j0c - 4;
    const int ln = t & 15, g = t >> 4;
    const int h = g & 1, pl = g >> 1;
    const int i = i0 + pl / 3, jx = j0c + pl % 3;
    const int p = i * HW + jx;
    int si = i - 3;  si = si < 0 ? 0 : (si > 89 ? 89 : si);
    int sj = jx - 3; sj = sj < 0 ? 0 : (sj > 89 ? 89 : sj);

    // ================= P1: K->LDS, Q->LDS, weights-hi->LDS, V->regs ========
    const int c4 = (t & 15) << 2;
    int hps[4], hpix[4];
    #pragma unroll
    for (int it = 0; it < 4; ++it) {
        hps[it] = it * 36 + (t >> 4);
        hpix[it] = halo_pix(hps[it] < HALO_N ? hps[it] : 0, hr0, hc0);
    }
    float pr[4] = {0.f, 0.f, 0.f, 0.f};
    if (HASPREV) {
        #pragma unroll
        for (int k = 0; k < 4; ++k)
            pr[k] = prev[(p * 2 + h) * ASTRIDE + ((k << 4) | ln)];
    }
    #pragma unroll
    for (int it = 0; it < 4; ++it)
        if (hps[it] < HALO_N)
            *(float4*)&big[swz(hps[it], c4)] =
                *(const float4*)&qkv[hpix[it] * QN + 64 + c4];
    if (t < 288) {
        int gq = t >> 3, dc = (t & 7) << 2;
        int plq = gq >> 1;
        int pq = (i0 + plq / 3) * HW + j0c + plq % 3;
        *(float4*)&qsx[gq * 32 + dc] = *(const float4*)&qkv[pq * QN + (gq & 1) * 32 + dc];
    }
    if (!LAST) {
        #pragma unroll
        for (int it = 0; it < 2; ++it) {          // W' rows 132..191
            int l = it * NT + t;
            if (l < 960) {
                int j = 132 + (l >> 4), cs = (l & 15) << 2;
                *(float4*)&big[swz(j, cs)] = *(const float4*)&wp[j * 64 + cs];
            }
        }
    } else {
        #pragma unroll
        for (int it = 0; it < 2; ++it) {          // pw -> rows 132..195
            int l = it * NT + t;
            if (l < 1024) {
                int j = l >> 4, cs = (l & 15) << 2;
                *(float4*)&big[swz(132 + j, cs)] = *(const float4*)&wp[j * 64 + cs];
            }
        }
    }
    float4 vreg[4];                               // V-halo held to B2 (16 VGPR)
    #pragma unroll
    for (int it = 0; it < 4; ++it)
        if (hps[it] < HALO_N)
            vreg[it] = *(const float4*)&qkv[hpix[it] * QN + 128 + c4];
    __syncthreads();                                            // B1
    // ================= QK (LDS) ===========================================
    const int hbase = (si - hr0) * 11 + (sj - hc0);
    int hofs[4], rbidx[4], okm[4];
    #pragma unroll
    for (int k = 0; k < 4; ++k) {
        int n = (k << 4) | ln;
        okm[k] = (n <= 48);
        int nn = okm[k] ? n : 0;
        int a = (nn * 147) >> 10;                 // nn / 7
        int b = nn - a * 7;
        hofs[k] = hbase + a * 11 + b;
        rbidx[k] = a * 13 + b;
    }
    float s0 = 0.f, s1 = 0.f, s2 = 0.f, s3 = 0.f;
    #pragma unroll
    for (int dc = 0; dc < 8; ++dc) {
        float4 qv = *(const float4*)&qsx[g * 32 + dc * 4];
        float4 k0 = *(const float4*)&big[swz(hofs[0], dc * 4)];
        float4 k1 = *(const float4*)&big[swz(hofs[1], dc * 4)];
        float4 k2 = *(const float4*)&big[swz(hofs[2], dc * 4)];
        float4 k3 = *(const float4*)&big[swz(hofs[3], dc * 4)];
        s0 = fmaf(qv.x, k0.x, s0); s0 = fmaf(qv.y, k0.y, s0);
        s0 = fmaf(qv.z, k0.z, s0); s0 = fmaf(qv.w, k0.w, s0);
        s1 = fmaf(qv.x, k1.x, s1); s1 = fmaf(qv.y, k1.y, s1);
        s1 = fmaf(qv.z, k1.z, s1); s1 = fmaf(qv.w, k1.w, s1);
        s2 = fmaf(qv.x, k2.x, s2); s2 = fmaf(qv.y, k2.y, s2);
        s2 = fmaf(qv.z, k2.z, s2); s2 = fmaf(qv.w, k2.w, s2);
        s3 = fmaf(qv.x, k3.x, s3); s3 = fmaf(qv.y, k3.y, s3);
        s3 = fmaf(qv.z, k3.z, s3); s3 = fmaf(qv.w, k3.w, s3);
    }
    float lg[4] = {s0, s1, s2, s3};
    {
        const float* rp = rpb + h * 169;
        const int rbase = (si - i + 6) * 13 + (sj - jx + 6);
        #pragma unroll
        for (int k = 0; k < 4; ++k) {
            float bv = rp[rbase + rbidx[k]];
            float l2 = fmaf(lg[k], SCALE, bv + pr[k]);
            lg[k] = okm[k] ? l2 : -1e30f;
        }
    }
    float mx = fmaxf(fmaxf(lg[0], lg[1]), fmaxf(lg[2], lg[3]));
    mx = fmaxf(mx, __shfl_xor(mx, 1));
    mx = fmaxf(mx, __shfl_xor(mx, 2));
    mx = fmaxf(mx, __shfl_xor(mx, 4));
    mx = fmaxf(mx, __shfl_xor(mx, 8));
    float wk[4];
    float sum = 0.f;
    #pragma unroll
    for (int k = 0; k < 4; ++k) { wk[k] = expf(lg[k] - mx); sum += wk[k]; }
    sum += __shfl_xor(sum, 1);
    sum += __shfl_xor(sum, 2);
    sum += __shfl_xor(sum, 4);
    sum += __shfl_xor(sum, 8);
    const float inv = 1.f / sum;
    wk[0] *= inv; wk[1] *= inv; wk[2] *= inv; wk[3] *= inv;
    att_s[g * ASTRIDE + ln]      = wk[0];
    att_s[g * ASTRIDE + 16 + ln] = wk[1];
    att_s[g * ASTRIDE + 32 + ln] = wk[2];
    if (ln == 0) att_s[g * ASTRIDE + 48] = wk[3];
    if (!LAST) {
        const int gp = p * 2 + h;
        if (ln < 12)
            *(float4*)&cur[gp * ASTRIDE + ln * 4] =
                *(const float4*)&att_s[g * ASTRIDE + ln * 4];
        else if (ln == 12)
            cur[gp * ASTRIDE + 48] = att_s[g * ASTRIDE + 48];
    }
    __syncthreads();                                            // B2 (K reads done)
    // V regs -> LDS; issue W'lo loads (held to B4: 16 VGPR)
    #pragma unroll
    for (int it = 0; it < 4; ++it)
        if (hps[it] < HALO_N)
            *(float4*)&big[swz(hps[it], c4)] = vreg[it];
    float4 wlo[4];
    if (!LAST) {
        #pragma unroll
        for (int it = 0; it < 4; ++it) {
            int l = it * NT + t;
            if (l < 2112)
                wlo[it] = *(const float4*)&wp[(l >> 4) * 64 + ((l & 15) << 2)];
        }
    }
    __syncthreads();                                            // B3
    // ================= PV (LDS): lane owns dims {ln*2, ln*2+1} ============
    {
        const int vcol = h * 32 + ln * 2;
        float a0 = 0.f, a1 = 0.f;
        #pragma unroll
        for (int kk = 0; kk < 12; ++kk) {
            float4 w4 = *(const float4*)&att_s[g * ASTRIDE + kk * 4];
            #pragma unroll
            for (int c = 0; c < 4; ++c) {
                int n = kk * 4 + c;
                int a = n / 7, b = n % 7;        // compile-time after unroll
                float w = (c == 0) ? w4.x : (c == 1) ? w4.y : (c == 2) ? w4.z : w4.w;
                float2 v = *(const float2*)&big[swz(hbase + a * 11 + b, vcol)];
                a0 = fmaf(w, v.x, a0); a1 = fmaf(w, v.y, a1);
            }
        }
        float w48 = att_s[g * ASTRIDE + 48];
        float2 v48 = *(const float2*)&big[swz(hbase + 6 * 11 + 6, vcol)];
        a0 = fmaf(w48, v48.x, a0); a1 = fmaf(w48, v48.y, a1);
        *(float2*)&qsx[swz(pl, vcol)] = make_float2(a0, a1);
    }
    __syncthreads();                                            // B4 (V reads done)
    if (!LAST) {
        // W'lo regs -> LDS rows 0..131
        #pragma unroll
        for (int it = 0; it < 4; ++it) {
            int l = it * NT + t;
            if (l < 2112)
                *(float4*)&big[swz(l >> 4, (l & 15) << 2)] = wlo[it];
        }
        __syncthreads();                                        // B5
        fused_gemm(qsx, big, bp, qkvn, i0, j0c, t);
        return;
    }
    // ================= LAST: proj + transposed output =====================
    const int pxg = t % 9, jo = t / 9;
    float pa0 = bp[jo], pa1 = pa0;
    #pragma unroll
    for (int cc = 0; cc < 16; ++cc) {
        float4 xv0 = *(const float4*)&qsx[swz(pxg * 2, cc * 4)];
        float4 xv1 = *(const float4*)&qsx[swz(pxg * 2 + 1, cc * 4)];
        float4 wv  = *(const float4*)&big[swz(132 + jo, cc * 4)];
        pa0 = fmaf(xv0.x, wv.x, pa0); pa0 = fmaf(xv0.y, wv.y, pa0);
        pa0 = fmaf(xv0.z, wv.z, pa0); pa0 = fmaf(xv0.w, wv.w, pa0);
        pa1 = fmaf(xv1.x, wv.x, pa1); pa1 = fmaf(xv1.y, wv.y, pa1);
        pa1 = fmaf(xv1.z, wv.z, pa1); pa1 = fmaf(xv1.w, wv.w, pa1);
    }
    __syncthreads();                                            // B5 (qsx reads done)
    qsx[swz(pxg * 2, jo)]     = pa0;
    qsx[swz(pxg * 2 + 1, jo)] = pa1;
    __syncthreads();                                            // B6
    #pragma unroll
    for (int it = 0; it < 2; ++it) {
        int l = it * NT + t;
        int px = l % 18, c = l / 18;
        outp[c * NPIX + (i0 + px / 3) * HW + j0c + px % 3] = qsx[swz(px, c)];
    }
}

extern "C" void kernel_launch(void* const* d_in, const int* in_sizes, int n_in,
                              void* d_out, int out_size, void* d_ws, size_t ws_size,
                              hipStream_t stream)
{
    const float* x   = (const float*)d_in[0];
    const float* qw  = (const float*)d_in[1];   // (3,192,64)
    const float* qb  = (const float*)d_in[2];   // (3,192)
    const float* pw  = (const float*)d_in[3];   // (3,64,64)
    const float* pb  = (const float*)d_in[4];   // (3,64)
    const float* rpb = (const float*)d_in[5];   // (3,2,13,13)
    float* out = (float*)d_out;
    float* ws  = (float*)d_ws;

    float* qkvA  = ws;                   // 1,769,472 floats
    float* qkvB  = qkvA + 1769472;       // 1,769,472
    float* attA  = qkvB + 1769472;       //   958,464 (18432 * 52)
    float* attB  = attA + 958464;        //   958,464
    float* wfuse = attB + 958464;        //    24,576 (2 x 192 x 64)
    float* bfuse = wfuse + 24576;        //       384

    k_prep<<<96, 256, 0, stream>>>(qw, qb, pw, pb, wfuse, bfuse);
    k_qkv0<<<512, NT, 0, stream>>>(x, qw, qb, qkvA);
    k_stage<0, 0><<<512, NT, 0, stream>>>(qkvA, rpb,       nullptr, attA,
                                          wfuse,         bfuse,       qkvB, nullptr);
    k_stage<1, 0><<<512, NT, 0, stream>>>(qkvB, rpb + 338, attA,    attB,
                                          wfuse + 12288, bfuse + 192, qkvA, nullptr);
    k_stage<1, 1><<<512, NT, 0, stream>>>(qkvA, rpb + 676, attB,    nullptr,
                                          pw + 8192,     pb + 128,    nullptr, out);
}